// Round 11
// baseline (142.836 us; speedup 1.0000x reference)
//
#include <hip/hip_runtime.h>
#include <hip/hip_bf16.h>

typedef __attribute__((ext_vector_type(8))) short short8;
typedef __attribute__((ext_vector_type(4))) short short4v;
typedef __attribute__((ext_vector_type(4))) float f32x4;

#define SCALE_QL 0.25504601521753316f   // (1/sqrt(32)) * log2(e)
#define LOG2E    1.4426950408889634f

__device__ __forceinline__ short f2bf(float f) {
  union { float f; unsigned u; } v; v.f = f;
  unsigned r = (v.u + 0x7fffu + ((v.u >> 16) & 1u)) >> 16;
  return (short)r;
}

union S8U { short8 v; __hip_bfloat162 h[4]; int2 d[2]; };
union W4U { int2 d; __hip_bfloat162 h[2]; };

__device__ __forceinline__ short8 pack8i(float4 a, float4 b) {
  S8U r;
  r.h[0] = __float22bfloat162_rn(make_float2(a.x, a.y));
  r.h[1] = __float22bfloat162_rn(make_float2(a.z, a.w));
  r.h[2] = __float22bfloat162_rn(make_float2(b.x, b.y));
  r.h[3] = __float22bfloat162_rn(make_float2(b.z, b.w));
  return r.v;
}

__device__ __forceinline__ short8 pack8f(f32x4 a, f32x4 b) {
  S8U r;
  r.h[0] = __float22bfloat162_rn(make_float2(a[0], a[1]));
  r.h[1] = __float22bfloat162_rn(make_float2(a[2], a[3]));
  r.h[2] = __float22bfloat162_rn(make_float2(b[0], b[1]));
  r.h[3] = __float22bfloat162_rn(make_float2(b[2], b[3]));
  return r.v;
}

__device__ __forceinline__ int2 pack4i(float a, float b, float c, float d) {
  W4U w;
  w.h[0] = __float22bfloat162_rn(make_float2(a, b));
  w.h[1] = __float22bfloat162_rn(make_float2(c, d));
  return w.d;
}

// ---------------------------------------------------------------------------
// k_prep: fragment-major pre-swizzle; bias table pre-multiplied by log2(e).
// ---------------------------------------------------------------------------
__global__ __launch_bounds__(256) void k_prep(
    const float* __restrict__ mask, const float* __restrict__ rpb,
    const float* __restrict__ qkvw, const float* __restrict__ pw,
    float* __restrict__ tabf, short* __restrict__ wfsw, short* __restrict__ pwsw)
{
  const int bid = blockIdx.x, tid = threadIdx.x;
  if (bid < 256) {
    const int wdx = bid >> 2, hh = bid & 3;
    for (int i = 0; i < 4; ++i) {
      int e = tid + i * 256;                 // [mt][nt][lane]
      int mt = e >> 8, nt = (e >> 6) & 3, ln = e & 63;
      int l = ln & 15, g = ln >> 4;
      int m = mt * 16 + l, n0 = nt * 16 + g * 4;
      float vv[4];
      #pragma unroll
      for (int j = 0; j < 4; ++j) {
        int n = n0 + j;
        float val;
        if (n >= 49)      val = -1e30f;
        else if (m >= 49) val = 0.0f;
        else {
          int mi = (m * 37) >> 8, mj = m - mi * 7;
          int ni = (n * 37) >> 8, nj = n - ni * 7;
          int ridx = (mi - ni + 6) * 13 + (mj - nj + 6);
          val = mask[(size_t)wdx * 2401 + m * 49 + n] + rpb[ridx * 4 + hh];
        }
        vv[j] = val * LOG2E;
      }
      float4* dst = reinterpret_cast<float4*>(&tabf[((size_t)bid * 1024 + e) * 4]);
      *dst = make_float4(vv[0], vv[1], vv[2], vv[3]);
    }
  } else {
    int e0 = (bid - 256) * 256 + tid;
    for (int i = 0; i < 4; ++i) {
      int e = e0 + i * 2048;
      const float* src;
      short* dst;
      if (e < 6144) {
        int hh = e / 1536, rem = e - hh * 1536;
        int slot = rem >> 8, ks = (rem >> 6) & 3, ln = rem & 63;
        int l = ln & 15, g = ln >> 4;
        int r = (slot >> 1) * 128 + hh * 32 + (slot & 1) * 16 + l;
        int c = ks * 32 + g * 8;
        src = &qkvw[(size_t)r * 128 + c];
        dst = wfsw + (size_t)e * 8;
      } else {
        int p = e - 6144;
        int nt = p >> 8, ks = (p >> 6) & 3, ln = p & 63;
        int l = ln & 15, g = ln >> 4;
        int r = nt * 16 + l, c = ks * 32 + g * 8;
        src = &pw[(size_t)r * 128 + c];
        dst = pwsw + (size_t)p * 8;
      }
      float4 a = *reinterpret_cast<const float4*>(src);
      float4 b = *reinterpret_cast<const float4*>(src + 4);
      *reinterpret_cast<short8*>(dst) = pack8i(a, b);
    }
  }
}

// ---------------------------------------------------------------------------
// k_fused: block = 4 waves (one per head) x TWO windows (A,B).
// Each wave runs both windows' pipelines phase-interleaved: two independent
// dependency chains per wave double the schedulable ILP; shared weight /
// proj-fragment loads feed both windows' MFMAs; 3 barriers per 2 windows.
// ---------------------------------------------------------------------------
__global__ __launch_bounds__(256) void k_fused(
    const float* __restrict__ x, const float* __restrict__ qkvb,
    const float* __restrict__ pb, const float* __restrict__ tabf,
    const short* __restrict__ wfsw, const short* __restrict__ pwsw,
    float* __restrict__ out)
{
  __shared__ short xs[2][64 * 136];     // x bf16 per window; later ao overlay
  const int tid = threadIdx.x;
  const int lane = tid & 63;
  const int h = tid >> 6;
  const int l15 = lane & 15, grp = lane >> 4;
  const int winA = blockIdx.x * 2;
  const size_t xbA = (size_t)winA * 49 * 128;
  const size_t xbB = xbA + 49 * 128;
  const short* wfh = wfsw + (size_t)h * 6 * 4 * 64 * 8;
  const f32x4 zero4 = (f32x4){0, 0, 0, 0};

  // ---- stage both windows' x (fp32 -> bf16, coalesced) + zero pads ----
  #pragma unroll
  for (int i = 0; i < 13; ++i) {
    int idx = tid + i * 256;
    if (idx < 3136) {
      int w = idx >= 1568;
      int rem = idx - (w ? 1568 : 0);
      int r = rem >> 5, c4 = rem & 31;
      float4 v = *reinterpret_cast<const float4*>(
          &x[(w ? xbB : xbA) + (size_t)r * 128 + c4 * 4]);
      short4v s; s[0] = f2bf(v.x); s[1] = f2bf(v.y); s[2] = f2bf(v.z); s[3] = f2bf(v.w);
      *reinterpret_cast<short4v*>(&xs[w][r * 136 + c4 * 4]) = s;
    }
  }
  #pragma unroll
  for (int i = 0; i < 8; ++i) {
    int idx = tid + i * 256;
    if (idx < 1920) {
      int w = idx >= 960;
      int rem = idx - (w ? 960 : 0);
      int r = 49 + (rem >> 6), c = rem & 63;
      *reinterpret_cast<int*>(&xs[w][r * 136 + c * 2]) = 0;
    }
  }
  __syncthreads();

  // ---- QK gemm (swapped) for one window: cs -> Qp, Kp ----
  auto qk_gemm = [&](const short* cs, short8 (&Qp)[4], short8 (&Kp)[4]) {
    f32x4 qk[4][4];
    #pragma unroll
    for (int nt = 0; nt < 4; ++nt) {
      int base = (nt < 2 ? 0 : 128) + h * 32 + (nt & 1) * 16 + grp * 4;
      float4 b4 = *reinterpret_cast<const float4*>(&qkvb[base]);
      #pragma unroll
      for (int tt = 0; tt < 4; ++tt) qk[tt][nt] = (f32x4){b4.x, b4.y, b4.z, b4.w};
    }
    short8 wfc[4], wfn[4];
    #pragma unroll
    for (int nt = 0; nt < 4; ++nt)
      wfc[nt] = *reinterpret_cast<const short8*>(wfh + (((size_t)nt * 4 + 0) * 64 + lane) * 8);
    #pragma unroll
    for (int ks = 0; ks < 4; ++ks) {
      if (ks < 3) {
        #pragma unroll
        for (int nt = 0; nt < 4; ++nt)
          wfn[nt] = *reinterpret_cast<const short8*>(wfh + (((size_t)nt * 4 + ks + 1) * 64 + lane) * 8);
        __builtin_amdgcn_sched_barrier(0);
      }
      #pragma unroll
      for (int tt = 0; tt < 4; ++tt) {
        short8 xf = *reinterpret_cast<const short8*>(&cs[(tt * 16 + l15) * 136 + ks * 32 + grp * 8]);
        #pragma unroll
        for (int nt = 0; nt < 4; ++nt)
          qk[tt][nt] = __builtin_amdgcn_mfma_f32_16x16x32_bf16(wfc[nt], xf, qk[tt][nt], 0, 0, 0);
      }
      #pragma unroll
      for (int nt = 0; nt < 4; ++nt) wfc[nt] = wfn[nt];
    }
    #pragma unroll
    for (int tt = 0; tt < 4; ++tt) {
      Qp[tt] = pack8f(qk[tt][0] * SCALE_QL, qk[tt][1] * SCALE_QL);
      Kp[tt] = pack8f(qk[tt][2], qk[tt][3]);
    }
  };

  // ---- V gemm for one window: cs -> Vp[k2*2+dt] ----
  auto v_gemm = [&](const short* cs, short8 (&Vp)[4]) {
    f32x4 vacc[4][2];
    #pragma unroll
    for (int dt = 0; dt < 2; ++dt) {
      float bv = qkvb[256 + h * 32 + dt * 16 + l15];
      #pragma unroll
      for (int tt = 0; tt < 4; ++tt) vacc[tt][dt] = (f32x4){bv, bv, bv, bv};
    }
    short8 wvc[2], wvn[2];
    #pragma unroll
    for (int dt = 0; dt < 2; ++dt)
      wvc[dt] = *reinterpret_cast<const short8*>(wfh + ((((size_t)4 + dt) * 4 + 0) * 64 + lane) * 8);
    #pragma unroll
    for (int ks = 0; ks < 4; ++ks) {
      if (ks < 3) {
        #pragma unroll
        for (int dt = 0; dt < 2; ++dt)
          wvn[dt] = *reinterpret_cast<const short8*>(wfh + ((((size_t)4 + dt) * 4 + ks + 1) * 64 + lane) * 8);
        __builtin_amdgcn_sched_barrier(0);
      }
      #pragma unroll
      for (int tt = 0; tt < 4; ++tt) {
        short8 xf = *reinterpret_cast<const short8*>(&cs[(tt * 16 + l15) * 136 + ks * 32 + grp * 8]);
        #pragma unroll
        for (int dt = 0; dt < 2; ++dt)
          vacc[tt][dt] = __builtin_amdgcn_mfma_f32_16x16x32_bf16(xf, wvc[dt], vacc[tt][dt], 0, 0, 0);
      }
      #pragma unroll
      for (int dt = 0; dt < 2; ++dt) wvc[dt] = wvn[dt];
    }
    #pragma unroll
    for (int k2 = 0; k2 < 2; ++k2)
      #pragma unroll
      for (int dt = 0; dt < 2; ++dt)
        Vp[k2 * 2 + dt] = pack8f(vacc[2 * k2][dt], vacc[2 * k2 + 1][dt]);
  };

  short8 QpA[4], KpA[4], QpB[4], KpB[4], VpA[4], VpB[4];
  qk_gemm(xs[0], QpA, KpA);
  qk_gemm(xs[1], QpB, KpB);
  v_gemm(xs[0], VpA);
  v_gemm(xs[1], VpB);

  const float* tbaseA = tabf + (((size_t)((winA & 63) * 4 + h)) * 16) * 256;
  const float* tbaseB = tabf + (((size_t)(((winA + 1) & 63) * 4 + h)) * 16) * 256;
  __syncthreads();   // B1: all xs reads done -> ao overlay allowed

  // ---- softmax + PV for one window at tile mt ----
  auto softmax_pv = [&](int mt, f32x4 (&s4)[4], const float4 (&tb)[4],
                        const short8 (&Vp)[4], short* cs) {
    #pragma unroll
    for (int nt = 0; nt < 4; ++nt) {
      s4[nt][0] += tb[nt].x;
      s4[nt][1] += tb[nt].y;
      s4[nt][2] += tb[nt].z;
      s4[nt][3] += tb[nt].w;
    }
    float mx = s4[0][0];
    #pragma unroll
    for (int nt = 0; nt < 4; ++nt)
      #pragma unroll
      for (int r = 0; r < 4; ++r) mx = fmaxf(mx, s4[nt][r]);
    mx = fmaxf(mx, __shfl_xor(mx, 16));
    mx = fmaxf(mx, __shfl_xor(mx, 32));
    float sum = 0.f;
    #pragma unroll
    for (int nt = 0; nt < 4; ++nt)
      #pragma unroll
      for (int r = 0; r < 4; ++r) {
        s4[nt][r] = __builtin_amdgcn_exp2f(s4[nt][r] - mx);
        sum += s4[nt][r];
      }
    sum += __shfl_xor(sum, 16);
    sum += __shfl_xor(sum, 32);
    float ri = 1.0f / sum;
    #pragma unroll
    for (int nt = 0; nt < 4; ++nt) s4[nt] *= ri;
    short8 Pp0 = pack8f(s4[0], s4[1]);
    short8 Pp1 = pack8f(s4[2], s4[3]);
    const int m0 = mt * 16 + l15;
    #pragma unroll
    for (int dt = 0; dt < 2; ++dt) {
      f32x4 ot = __builtin_amdgcn_mfma_f32_16x16x32_bf16(Vp[dt], Pp0, zero4, 0, 0, 0);
      ot = __builtin_amdgcn_mfma_f32_16x16x32_bf16(Vp[2 + dt], Pp1, ot, 0, 0, 0);
      *reinterpret_cast<int2*>(&cs[m0 * 136 + h * 32 + dt * 16 + grp * 4]) =
          pack4i(ot[0], ot[1], ot[2], ot[3]);
    }
  };

  // ---- per query-column-tile: both windows interleaved ----
  #pragma unroll
  for (int mt = 0; mt < 4; ++mt) {
    float4 tA[4], tB[4];
    #pragma unroll
    for (int nt = 0; nt < 4; ++nt) {
      tA[nt] = *reinterpret_cast<const float4*>(tbaseA + (((size_t)mt * 4 + nt) * 64 + lane) * 4);
      tB[nt] = *reinterpret_cast<const float4*>(tbaseB + (((size_t)mt * 4 + nt) * 64 + lane) * 4);
    }
    f32x4 sA[4], sB[4];
    #pragma unroll
    for (int nt = 0; nt < 4; ++nt)
      sA[nt] = __builtin_amdgcn_mfma_f32_16x16x32_bf16(KpA[nt], QpA[mt], zero4, 0, 0, 0);
    #pragma unroll
    for (int nt = 0; nt < 4; ++nt)
      sB[nt] = __builtin_amdgcn_mfma_f32_16x16x32_bf16(KpB[nt], QpB[mt], zero4, 0, 0, 0);
    softmax_pv(mt, sA, tA, VpA, xs[0]);
    softmax_pv(mt, sB, tB, VpB, xs[1]);
  }
  __syncthreads();   // B2: ao complete -> proj reads

  // ---- proj for own 16 token rows of BOTH windows; shared B-fragments ----
  short8 afA[4], afB[4];
  #pragma unroll
  for (int ks = 0; ks < 4; ++ks) {
    afA[ks] = *reinterpret_cast<const short8*>(&xs[0][(h * 16 + l15) * 136 + ks * 32 + grp * 8]);
    afB[ks] = *reinterpret_cast<const short8*>(&xs[1][(h * 16 + l15) * 136 + ks * 32 + grp * 8]);
  }
  short8 bc[4], bn[4];
  #pragma unroll
  for (int ks = 0; ks < 4; ++ks)
    bc[ks] = *reinterpret_cast<const short8*>(pwsw + (((size_t)0 * 4 + ks) * 64 + lane) * 8);
  #pragma unroll
  for (int nt = 0; nt < 8; ++nt) {
    if (nt < 7) {
      #pragma unroll
      for (int ks = 0; ks < 4; ++ks)
        bn[ks] = *reinterpret_cast<const short8*>(pwsw + (((size_t)(nt + 1) * 4 + ks) * 64 + lane) * 8);
      __builtin_amdgcn_sched_barrier(0);
    }
    float bv = pb[nt * 16 + l15];
    f32x4 pcA = (f32x4){bv, bv, bv, bv};
    f32x4 pcB = (f32x4){bv, bv, bv, bv};
    #pragma unroll
    for (int ks = 0; ks < 4; ++ks) {
      pcA = __builtin_amdgcn_mfma_f32_16x16x32_bf16(afA[ks], bc[ks], pcA, 0, 0, 0);
      pcB = __builtin_amdgcn_mfma_f32_16x16x32_bf16(afB[ks], bc[ks], pcB, 0, 0, 0);
    }
    #pragma unroll
    for (int r = 0; r < 4; ++r) {
      int m = h * 16 + grp * 4 + r;
      if (m < 49) {
        out[xbA + (size_t)m * 128 + nt * 16 + l15] = pcA[r];
        out[xbB + (size_t)m * 128 + nt * 16 + l15] = pcB[r];
      }
    }
    #pragma unroll
    for (int ks = 0; ks < 4; ++ks) bc[ks] = bn[ks];
  }
}

// ---------------------------------------------------------------------------
extern "C" void kernel_launch(void* const* d_in, const int* in_sizes, int n_in,
                              void* d_out, int out_size, void* d_ws, size_t ws_size,
                              hipStream_t stream) {
  const float* x    = (const float*)d_in[0];
  const float* mask = (const float*)d_in[1];
  const float* qkvw = (const float*)d_in[2];
  const float* qkvb = (const float*)d_in[3];
  const float* rpb  = (const float*)d_in[4];
  const float* pw   = (const float*)d_in[5];
  const float* pb   = (const float*)d_in[6];
  float* out = (float*)d_out;

  char* ws = (char*)d_ws;
  short* wfsw = (short*)ws;                  // 4*6*4*64*16 B = 98,304 B
  short* pwsw = (short*)(ws + 98304);        // 8*4*64*16 B  = 32,768 B
  float* tabf = (float*)(ws + 131072);       // 256*16*64*16 B = 4,194,304 B

  k_prep <<<264,  256, 0, stream>>>(mask, rpb, qkvw, pw, tabf, wfsw, pwsw);
  k_fused<<<2048, 256, 0, stream>>>(x, qkvb, pb, tabf, wfsw, pwsw, out);
}

// Round 12
// 80.062 us; speedup vs baseline: 1.7841x; 1.7841x over previous
//
#include <hip/hip_runtime.h>
#include <hip/hip_bf16.h>

typedef __attribute__((ext_vector_type(8))) short short8;
typedef __attribute__((ext_vector_type(4))) short short4v;
typedef __attribute__((ext_vector_type(4))) float f32x4;

#define SCALE_QL 0.25504601521753316f   // (1/sqrt(32)) * log2(e)
#define LOG2E    1.4426950408889634f

__device__ __forceinline__ short f2bf(float f) {
  union { float f; unsigned u; } v; v.f = f;
  unsigned r = (v.u + 0x7fffu + ((v.u >> 16) & 1u)) >> 16;
  return (short)r;
}

union S8U { short8 v; __hip_bfloat162 h[4]; int2 d[2]; };
union W4U { int2 d; __hip_bfloat162 h[2]; };

__device__ __forceinline__ short8 pack8i(float4 a, float4 b) {
  S8U r;
  r.h[0] = __float22bfloat162_rn(make_float2(a.x, a.y));
  r.h[1] = __float22bfloat162_rn(make_float2(a.z, a.w));
  r.h[2] = __float22bfloat162_rn(make_float2(b.x, b.y));
  r.h[3] = __float22bfloat162_rn(make_float2(b.z, b.w));
  return r.v;
}

__device__ __forceinline__ short8 pack8f(f32x4 a, f32x4 b) {
  S8U r;
  r.h[0] = __float22bfloat162_rn(make_float2(a[0], a[1]));
  r.h[1] = __float22bfloat162_rn(make_float2(a[2], a[3]));
  r.h[2] = __float22bfloat162_rn(make_float2(b[0], b[1]));
  r.h[3] = __float22bfloat162_rn(make_float2(b[2], b[3]));
  return r.v;
}

__device__ __forceinline__ int2 pack4i(float a, float b, float c, float d) {
  W4U w;
  w.h[0] = __float22bfloat162_rn(make_float2(a, b));
  w.h[1] = __float22bfloat162_rn(make_float2(c, d));
  return w.d;
}

// ---------------------------------------------------------------------------
// k_prep: fragment-major pre-swizzle; bias table pre-multiplied by log2(e).
// ---------------------------------------------------------------------------
__global__ __launch_bounds__(256) void k_prep(
    const float* __restrict__ mask, const float* __restrict__ rpb,
    const float* __restrict__ qkvw, const float* __restrict__ pw,
    float* __restrict__ tabf, short* __restrict__ wfsw, short* __restrict__ pwsw)
{
  const int bid = blockIdx.x, tid = threadIdx.x;
  if (bid < 256) {
    const int wdx = bid >> 2, hh = bid & 3;
    for (int i = 0; i < 4; ++i) {
      int e = tid + i * 256;                 // [mt][nt][lane]
      int mt = e >> 8, nt = (e >> 6) & 3, ln = e & 63;
      int l = ln & 15, g = ln >> 4;
      int m = mt * 16 + l, n0 = nt * 16 + g * 4;
      float vv[4];
      #pragma unroll
      for (int j = 0; j < 4; ++j) {
        int n = n0 + j;
        float val;
        if (n >= 49)      val = -1e30f;
        else if (m >= 49) val = 0.0f;
        else {
          int mi = (m * 37) >> 8, mj = m - mi * 7;
          int ni = (n * 37) >> 8, nj = n - ni * 7;
          int ridx = (mi - ni + 6) * 13 + (mj - nj + 6);
          val = mask[(size_t)wdx * 2401 + m * 49 + n] + rpb[ridx * 4 + hh];
        }
        vv[j] = val * LOG2E;
      }
      float4* dst = reinterpret_cast<float4*>(&tabf[((size_t)bid * 1024 + e) * 4]);
      *dst = make_float4(vv[0], vv[1], vv[2], vv[3]);
    }
  } else {
    int e0 = (bid - 256) * 256 + tid;
    for (int i = 0; i < 4; ++i) {
      int e = e0 + i * 2048;
      const float* src;
      short* dst;
      if (e < 6144) {
        int hh = e / 1536, rem = e - hh * 1536;
        int slot = rem >> 8, ks = (rem >> 6) & 3, ln = rem & 63;
        int l = ln & 15, g = ln >> 4;
        int r = (slot >> 1) * 128 + hh * 32 + (slot & 1) * 16 + l;
        int c = ks * 32 + g * 8;
        src = &qkvw[(size_t)r * 128 + c];
        dst = wfsw + (size_t)e * 8;
      } else {
        int p = e - 6144;
        int nt = p >> 8, ks = (p >> 6) & 3, ln = p & 63;
        int l = ln & 15, g = ln >> 4;
        int r = nt * 16 + l, c = ks * 32 + g * 8;
        src = &pw[(size_t)r * 128 + c];
        dst = pwsw + (size_t)p * 8;
      }
      float4 a = *reinterpret_cast<const float4*>(src);
      float4 b = *reinterpret_cast<const float4*>(src + 4);
      *reinterpret_cast<short8*>(dst) = pack8i(a, b);
    }
  }
}

// ---------------------------------------------------------------------------
// k_fused: one window per block, 4 waves (one per head) — round-10 structure.
// NEW: XCD-affinity block swizzle (each XCD sees only wdx === XCD mod 8 ->
// its 512 KB bias-table slice is L2-resident) + cvt_pk staging conversion.
// ---------------------------------------------------------------------------
__global__ __launch_bounds__(256, 3) void k_fused(
    const float* __restrict__ x, const float* __restrict__ qkvb,
    const float* __restrict__ pb, const float* __restrict__ tabf,
    const short* __restrict__ wfsw, const short* __restrict__ pwsw,
    float* __restrict__ out)
{
  __shared__ short xs[64 * 136];       // x bf16 [64][136]; later ao overlay
  const int tid = threadIdx.x;
  const int lane = tid & 63;
  const int h = tid >> 6;
  const int l15 = lane & 15, grp = lane >> 4;
  // XCD-affinity swizzle: bijective on [0,4096); wdx mod 8 == blockIdx mod 8
  const int bswz = blockIdx.x;
  const int gwin = ((bswz >> 6) << 6) + (bswz & 7) + ((bswz >> 3) & 7) * 8;
  const int wdx = gwin & 63;
  const size_t xbase = (size_t)gwin * 49 * 128;
  const short* wfh = wfsw + (size_t)h * 6 * 4 * 64 * 8;
  const f32x4 zero4 = (f32x4){0, 0, 0, 0};

  // ---- stage x (fp32 -> bf16 via cvt_pk, coalesced) + zero pad rows ----
  #pragma unroll
  for (int i = 0; i < 7; ++i) {
    int idx = tid + i * 256;
    if (idx < 1568) {
      int r = idx >> 5, c4 = idx & 31;
      float4 v = *reinterpret_cast<const float4*>(&x[xbase + (size_t)r * 128 + c4 * 4]);
      *reinterpret_cast<int2*>(&xs[r * 136 + c4 * 4]) = pack4i(v.x, v.y, v.z, v.w);
    }
  }
  #pragma unroll
  for (int i = 0; i < 4; ++i) {
    int idx = tid + i * 256;
    if (idx < 960) {
      int r = 49 + (idx >> 6), c = idx & 63;
      *reinterpret_cast<int*>(&xs[r * 136 + c * 2]) = 0;
    }
  }
  __syncthreads();

  // ---- QK gemm (swapped): qk[tt][nt] = mfma(wf, xf); wf ping-pong ----
  f32x4 qk[4][4];
  #pragma unroll
  for (int nt = 0; nt < 4; ++nt) {
    int base = (nt < 2 ? 0 : 128) + h * 32 + (nt & 1) * 16 + grp * 4;
    float4 b4 = *reinterpret_cast<const float4*>(&qkvb[base]);
    #pragma unroll
    for (int tt = 0; tt < 4; ++tt) qk[tt][nt] = (f32x4){b4.x, b4.y, b4.z, b4.w};
  }
  {
    short8 wfc[4], wfn[4];
    #pragma unroll
    for (int nt = 0; nt < 4; ++nt)
      wfc[nt] = *reinterpret_cast<const short8*>(wfh + (((size_t)nt * 4 + 0) * 64 + lane) * 8);
    #pragma unroll
    for (int ks = 0; ks < 4; ++ks) {
      if (ks < 3) {
        #pragma unroll
        for (int nt = 0; nt < 4; ++nt)
          wfn[nt] = *reinterpret_cast<const short8*>(wfh + (((size_t)nt * 4 + ks + 1) * 64 + lane) * 8);
        __builtin_amdgcn_sched_barrier(0);
      }
      #pragma unroll
      for (int tt = 0; tt < 4; ++tt) {
        short8 xf = *reinterpret_cast<const short8*>(&xs[(tt * 16 + l15) * 136 + ks * 32 + grp * 8]);
        #pragma unroll
        for (int nt = 0; nt < 4; ++nt)
          qk[tt][nt] = __builtin_amdgcn_mfma_f32_16x16x32_bf16(wfc[nt], xf, qk[tt][nt], 0, 0, 0);
      }
      #pragma unroll
      for (int nt = 0; nt < 4; ++nt) wfc[nt] = wfn[nt];
    }
  }
  short8 Qp[4], Kp[4];
  #pragma unroll
  for (int tt = 0; tt < 4; ++tt) {
    Qp[tt] = pack8f(qk[tt][0] * SCALE_QL, qk[tt][1] * SCALE_QL);  // log2e folded
    Kp[tt] = pack8f(qk[tt][2], qk[tt][3]);
  }

  // ---- V gemm (normal orientation), wv ping-pong ----
  short8 Vp[2][2];
  {
    f32x4 vacc[4][2];
    #pragma unroll
    for (int dt = 0; dt < 2; ++dt) {
      float bv = qkvb[256 + h * 32 + dt * 16 + l15];
      #pragma unroll
      for (int tt = 0; tt < 4; ++tt) vacc[tt][dt] = (f32x4){bv, bv, bv, bv};
    }
    short8 wvc[2], wvn[2];
    #pragma unroll
    for (int dt = 0; dt < 2; ++dt)
      wvc[dt] = *reinterpret_cast<const short8*>(wfh + ((((size_t)4 + dt) * 4 + 0) * 64 + lane) * 8);
    #pragma unroll
    for (int ks = 0; ks < 4; ++ks) {
      if (ks < 3) {
        #pragma unroll
        for (int dt = 0; dt < 2; ++dt)
          wvn[dt] = *reinterpret_cast<const short8*>(wfh + ((((size_t)4 + dt) * 4 + ks + 1) * 64 + lane) * 8);
        __builtin_amdgcn_sched_barrier(0);
      }
      #pragma unroll
      for (int tt = 0; tt < 4; ++tt) {
        short8 xf = *reinterpret_cast<const short8*>(&xs[(tt * 16 + l15) * 136 + ks * 32 + grp * 8]);
        #pragma unroll
        for (int dt = 0; dt < 2; ++dt)
          vacc[tt][dt] = __builtin_amdgcn_mfma_f32_16x16x32_bf16(xf, wvc[dt], vacc[tt][dt], 0, 0, 0);
      }
      #pragma unroll
      for (int dt = 0; dt < 2; ++dt) wvc[dt] = wvn[dt];
    }
    #pragma unroll
    for (int k2 = 0; k2 < 2; ++k2)
      #pragma unroll
      for (int dt = 0; dt < 2; ++dt)
        Vp[k2][dt] = pack8f(vacc[2 * k2][dt], vacc[2 * k2 + 1][dt]);
  }

  // ---- prefetch bias-table for mt=0, then barrier (xs reads all done) ----
  const float* tbase = tabf + (((size_t)(wdx * 4 + h)) * 16) * 256;
  float4 tbc[4], tbn[4];
  #pragma unroll
  for (int nt = 0; nt < 4; ++nt)
    tbc[nt] = *reinterpret_cast<const float4*>(tbase + (((size_t)nt) * 64 + lane) * 4);
  __syncthreads();   // B1: ao overlay allowed

  // ---- per query-column-tile: S^T, exp2 softmax, PV -> ao overlay ----
  #pragma unroll
  for (int mt = 0; mt < 4; ++mt) {
    if (mt < 3) {
      #pragma unroll
      for (int nt = 0; nt < 4; ++nt)
        tbn[nt] = *reinterpret_cast<const float4*>(tbase + (((size_t)(mt + 1) * 4 + nt) * 64 + lane) * 4);
      __builtin_amdgcn_sched_barrier(0);
    }
    f32x4 s4[4];
    #pragma unroll
    for (int nt = 0; nt < 4; ++nt)
      s4[nt] = __builtin_amdgcn_mfma_f32_16x16x32_bf16(Kp[nt], Qp[mt], zero4, 0, 0, 0);
    const int m0 = mt * 16 + l15;
    #pragma unroll
    for (int nt = 0; nt < 4; ++nt) {
      s4[nt][0] += tbc[nt].x;
      s4[nt][1] += tbc[nt].y;
      s4[nt][2] += tbc[nt].z;
      s4[nt][3] += tbc[nt].w;
    }
    float mx = s4[0][0];
    #pragma unroll
    for (int nt = 0; nt < 4; ++nt)
      #pragma unroll
      for (int r = 0; r < 4; ++r) mx = fmaxf(mx, s4[nt][r]);
    mx = fmaxf(mx, __shfl_xor(mx, 16));
    mx = fmaxf(mx, __shfl_xor(mx, 32));
    float sum = 0.f;
    #pragma unroll
    for (int nt = 0; nt < 4; ++nt)
      #pragma unroll
      for (int r = 0; r < 4; ++r) {
        s4[nt][r] = __builtin_amdgcn_exp2f(s4[nt][r] - mx);
        sum += s4[nt][r];
      }
    sum += __shfl_xor(sum, 16);
    sum += __shfl_xor(sum, 32);
    float ri = 1.0f / sum;
    #pragma unroll
    for (int nt = 0; nt < 4; ++nt) s4[nt] *= ri;

    short8 Pp0 = pack8f(s4[0], s4[1]);
    short8 Pp1 = pack8f(s4[2], s4[3]);
    #pragma unroll
    for (int dt = 0; dt < 2; ++dt) {
      f32x4 ot = __builtin_amdgcn_mfma_f32_16x16x32_bf16(Vp[0][dt], Pp0, zero4, 0, 0, 0);
      ot = __builtin_amdgcn_mfma_f32_16x16x32_bf16(Vp[1][dt], Pp1, ot, 0, 0, 0);
      *reinterpret_cast<int2*>(&xs[m0 * 136 + h * 32 + dt * 16 + grp * 4]) =
          pack4i(ot[0], ot[1], ot[2], ot[3]);
    }
    #pragma unroll
    for (int nt = 0; nt < 4; ++nt) tbc[nt] = tbn[nt];
  }
  __syncthreads();   // B2: ao complete -> proj reads

  // ---- proj for own 16 token rows; nt-outer loop (pc = one f32x4) ----
  short8 afr[4];
  #pragma unroll
  for (int ks = 0; ks < 4; ++ks)
    afr[ks] = *reinterpret_cast<const short8*>(&xs[(h * 16 + l15) * 136 + ks * 32 + grp * 8]);
  short8 bc[4], bn[4];
  #pragma unroll
  for (int ks = 0; ks < 4; ++ks)
    bc[ks] = *reinterpret_cast<const short8*>(pwsw + (((size_t)0 * 4 + ks) * 64 + lane) * 8);
  #pragma unroll
  for (int nt = 0; nt < 8; ++nt) {
    if (nt < 7) {
      #pragma unroll
      for (int ks = 0; ks < 4; ++ks)
        bn[ks] = *reinterpret_cast<const short8*>(pwsw + (((size_t)(nt + 1) * 4 + ks) * 64 + lane) * 8);
      __builtin_amdgcn_sched_barrier(0);
    }
    float bv = pb[nt * 16 + l15];
    f32x4 pc = (f32x4){bv, bv, bv, bv};
    #pragma unroll
    for (int ks = 0; ks < 4; ++ks)
      pc = __builtin_amdgcn_mfma_f32_16x16x32_bf16(afr[ks], bc[ks], pc, 0, 0, 0);
    #pragma unroll
    for (int r = 0; r < 4; ++r) {
      int m = h * 16 + grp * 4 + r;
      if (m < 49)
        out[xbase + (size_t)m * 128 + nt * 16 + l15] = pc[r];
    }
    #pragma unroll
    for (int ks = 0; ks < 4; ++ks) bc[ks] = bn[ks];
  }
}

// ---------------------------------------------------------------------------
extern "C" void kernel_launch(void* const* d_in, const int* in_sizes, int n_in,
                              void* d_out, int out_size, void* d_ws, size_t ws_size,
                              hipStream_t stream) {
  const float* x    = (const float*)d_in[0];
  const float* mask = (const float*)d_in[1];
  const float* qkvw = (const float*)d_in[2];
  const float* qkvb = (const float*)d_in[3];
  const float* rpb  = (const float*)d_in[4];
  const float* pw   = (const float*)d_in[5];
  const float* pb   = (const float*)d_in[6];
  float* out = (float*)d_out;

  char* ws = (char*)d_ws;
  short* wfsw = (short*)ws;                  // 4*6*4*64*16 B = 98,304 B
  short* pwsw = (short*)(ws + 98304);        // 8*4*64*16 B  = 32,768 B
  float* tabf = (float*)(ws + 131072);       // 256*16*64*16 B = 4,194,304 B

  k_prep <<<264,  256, 0, stream>>>(mask, rpb, qkvw, pw, tabf, wfsw, pwsw);
  k_fused<<<4096, 256, 0, stream>>>(x, qkvb, pb, tabf, wfsw, pwsw, out);
}

// Round 13
// 76.650 us; speedup vs baseline: 1.8635x; 1.0445x over previous
//
#include <hip/hip_runtime.h>
#include <hip/hip_bf16.h>

typedef __attribute__((ext_vector_type(8))) short short8;
typedef __attribute__((ext_vector_type(4))) short short4v;
typedef __attribute__((ext_vector_type(4))) float f32x4;

#define SCALE_QL 0.25504601521753316f   // (1/sqrt(32)) * log2(e)
#define LOG2E    1.4426950408889634f

__device__ __forceinline__ short f2bf(float f) {
  union { float f; unsigned u; } v; v.f = f;
  unsigned r = (v.u + 0x7fffu + ((v.u >> 16) & 1u)) >> 16;
  return (short)r;
}

union S8U { short8 v; __hip_bfloat162 h[4]; int2 d[2]; };
union W4U { int2 d; __hip_bfloat162 h[2]; };

__device__ __forceinline__ short8 pack8i(float4 a, float4 b) {
  S8U r;
  r.h[0] = __float22bfloat162_rn(make_float2(a.x, a.y));
  r.h[1] = __float22bfloat162_rn(make_float2(a.z, a.w));
  r.h[2] = __float22bfloat162_rn(make_float2(b.x, b.y));
  r.h[3] = __float22bfloat162_rn(make_float2(b.z, b.w));
  return r.v;
}

__device__ __forceinline__ short8 pack8f(f32x4 a, f32x4 b) {
  S8U r;
  r.h[0] = __float22bfloat162_rn(make_float2(a[0], a[1]));
  r.h[1] = __float22bfloat162_rn(make_float2(a[2], a[3]));
  r.h[2] = __float22bfloat162_rn(make_float2(b[0], b[1]));
  r.h[3] = __float22bfloat162_rn(make_float2(b[2], b[3]));
  return r.v;
}

__device__ __forceinline__ int2 pack4i(float a, float b, float c, float d) {
  W4U w;
  w.h[0] = __float22bfloat162_rn(make_float2(a, b));
  w.h[1] = __float22bfloat162_rn(make_float2(c, d));
  return w.d;
}

// ---------------------------------------------------------------------------
// k_prep: fragment-major pre-swizzle; bias table pre-multiplied by log2(e).
// ---------------------------------------------------------------------------
__global__ __launch_bounds__(256) void k_prep(
    const float* __restrict__ mask, const float* __restrict__ rpb,
    const float* __restrict__ qkvw, const float* __restrict__ pw,
    float* __restrict__ tabf, short* __restrict__ wfsw, short* __restrict__ pwsw)
{
  const int bid = blockIdx.x, tid = threadIdx.x;
  if (bid < 256) {
    const int wdx = bid >> 2, hh = bid & 3;
    for (int i = 0; i < 4; ++i) {
      int e = tid + i * 256;                 // [mt][nt][lane]
      int mt = e >> 8, nt = (e >> 6) & 3, ln = e & 63;
      int l = ln & 15, g = ln >> 4;
      int m = mt * 16 + l, n0 = nt * 16 + g * 4;
      float vv[4];
      #pragma unroll
      for (int j = 0; j < 4; ++j) {
        int n = n0 + j;
        float val;
        if (n >= 49)      val = -1e30f;
        else if (m >= 49) val = 0.0f;
        else {
          int mi = (m * 37) >> 8, mj = m - mi * 7;
          int ni = (n * 37) >> 8, nj = n - ni * 7;
          int ridx = (mi - ni + 6) * 13 + (mj - nj + 6);
          val = mask[(size_t)wdx * 2401 + m * 49 + n] + rpb[ridx * 4 + hh];
        }
        vv[j] = val * LOG2E;
      }
      float4* dst = reinterpret_cast<float4*>(&tabf[((size_t)bid * 1024 + e) * 4]);
      *dst = make_float4(vv[0], vv[1], vv[2], vv[3]);
    }
  } else {
    int e0 = (bid - 256) * 256 + tid;
    for (int i = 0; i < 4; ++i) {
      int e = e0 + i * 2048;
      const float* src;
      short* dst;
      if (e < 6144) {
        int hh = e / 1536, rem = e - hh * 1536;
        int slot = rem >> 8, ks = (rem >> 6) & 3, ln = rem & 63;
        int l = ln & 15, g = ln >> 4;
        int r = (slot >> 1) * 128 + hh * 32 + (slot & 1) * 16 + l;
        int c = ks * 32 + g * 8;
        src = &qkvw[(size_t)r * 128 + c];
        dst = wfsw + (size_t)e * 8;
      } else {
        int p = e - 6144;
        int nt = p >> 8, ks = (p >> 6) & 3, ln = p & 63;
        int l = ln & 15, g = ln >> 4;
        int r = nt * 16 + l, c = ks * 32 + g * 8;
        src = &pw[(size_t)r * 128 + c];
        dst = pwsw + (size_t)p * 8;
      }
      float4 a = *reinterpret_cast<const float4*>(src);
      float4 b = *reinterpret_cast<const float4*>(src + 4);
      *reinterpret_cast<short8*>(dst) = pack8i(a, b);
    }
  }
}

// ---------------------------------------------------------------------------
// k_fused: round-12 structure (1 window/block, 4 waves, XCD swizzle).
// NEW: shuffle-free softmax — no max-subtraction (logits bounded, exp2 safe
// in fp32), row-sum via ones-MFMA (B-lane = output column), normalization
// folded into the O epilogue. Softmax phase = straight-line VALU + MFMA.
// ---------------------------------------------------------------------------
__global__ __launch_bounds__(256, 3) void k_fused(
    const float* __restrict__ x, const float* __restrict__ qkvb,
    const float* __restrict__ pb, const float* __restrict__ tabf,
    const short* __restrict__ wfsw, const short* __restrict__ pwsw,
    float* __restrict__ out)
{
  __shared__ short xs[64 * 136];       // x bf16 [64][136]; later ao overlay
  const int tid = threadIdx.x;
  const int lane = tid & 63;
  const int h = tid >> 6;
  const int l15 = lane & 15, grp = lane >> 4;
  // XCD-affinity swizzle: bijective on [0,4096); wdx mod 8 == blockIdx mod 8
  const int bswz = blockIdx.x;
  const int gwin = ((bswz >> 6) << 6) + (bswz & 7) + ((bswz >> 3) & 7) * 8;
  const int wdx = gwin & 63;
  const size_t xbase = (size_t)gwin * 49 * 128;
  const short* wfh = wfsw + (size_t)h * 6 * 4 * 64 * 8;
  const f32x4 zero4 = (f32x4){0, 0, 0, 0};

  // ---- stage x (fp32 -> bf16 via cvt_pk, coalesced) + zero pad rows ----
  #pragma unroll
  for (int i = 0; i < 7; ++i) {
    int idx = tid + i * 256;
    if (idx < 1568) {
      int r = idx >> 5, c4 = idx & 31;
      float4 v = *reinterpret_cast<const float4*>(&x[xbase + (size_t)r * 128 + c4 * 4]);
      *reinterpret_cast<int2*>(&xs[r * 136 + c4 * 4]) = pack4i(v.x, v.y, v.z, v.w);
    }
  }
  #pragma unroll
  for (int i = 0; i < 4; ++i) {
    int idx = tid + i * 256;
    if (idx < 960) {
      int r = 49 + (idx >> 6), c = idx & 63;
      *reinterpret_cast<int*>(&xs[r * 136 + c * 2]) = 0;
    }
  }
  __syncthreads();

  // ---- QK gemm (swapped): qk[tt][nt] = mfma(wf, xf); wf ping-pong ----
  f32x4 qk[4][4];
  #pragma unroll
  for (int nt = 0; nt < 4; ++nt) {
    int base = (nt < 2 ? 0 : 128) + h * 32 + (nt & 1) * 16 + grp * 4;
    float4 b4 = *reinterpret_cast<const float4*>(&qkvb[base]);
    #pragma unroll
    for (int tt = 0; tt < 4; ++tt) qk[tt][nt] = (f32x4){b4.x, b4.y, b4.z, b4.w};
  }
  {
    short8 wfc[4], wfn[4];
    #pragma unroll
    for (int nt = 0; nt < 4; ++nt)
      wfc[nt] = *reinterpret_cast<const short8*>(wfh + (((size_t)nt * 4 + 0) * 64 + lane) * 8);
    #pragma unroll
    for (int ks = 0; ks < 4; ++ks) {
      if (ks < 3) {
        #pragma unroll
        for (int nt = 0; nt < 4; ++nt)
          wfn[nt] = *reinterpret_cast<const short8*>(wfh + (((size_t)nt * 4 + ks + 1) * 64 + lane) * 8);
        __builtin_amdgcn_sched_barrier(0);
      }
      #pragma unroll
      for (int tt = 0; tt < 4; ++tt) {
        short8 xf = *reinterpret_cast<const short8*>(&xs[(tt * 16 + l15) * 136 + ks * 32 + grp * 8]);
        #pragma unroll
        for (int nt = 0; nt < 4; ++nt)
          qk[tt][nt] = __builtin_amdgcn_mfma_f32_16x16x32_bf16(wfc[nt], xf, qk[tt][nt], 0, 0, 0);
      }
      #pragma unroll
      for (int nt = 0; nt < 4; ++nt) wfc[nt] = wfn[nt];
    }
  }
  short8 Qp[4], Kp[4];
  #pragma unroll
  for (int tt = 0; tt < 4; ++tt) {
    Qp[tt] = pack8f(qk[tt][0] * SCALE_QL, qk[tt][1] * SCALE_QL);  // log2e folded
    Kp[tt] = pack8f(qk[tt][2], qk[tt][3]);
  }

  // ---- V gemm (normal orientation), wv ping-pong ----
  short8 Vp[2][2];
  {
    f32x4 vacc[4][2];
    #pragma unroll
    for (int dt = 0; dt < 2; ++dt) {
      float bv = qkvb[256 + h * 32 + dt * 16 + l15];
      #pragma unroll
      for (int tt = 0; tt < 4; ++tt) vacc[tt][dt] = (f32x4){bv, bv, bv, bv};
    }
    short8 wvc[2], wvn[2];
    #pragma unroll
    for (int dt = 0; dt < 2; ++dt)
      wvc[dt] = *reinterpret_cast<const short8*>(wfh + ((((size_t)4 + dt) * 4 + 0) * 64 + lane) * 8);
    #pragma unroll
    for (int ks = 0; ks < 4; ++ks) {
      if (ks < 3) {
        #pragma unroll
        for (int dt = 0; dt < 2; ++dt)
          wvn[dt] = *reinterpret_cast<const short8*>(wfh + ((((size_t)4 + dt) * 4 + ks + 1) * 64 + lane) * 8);
        __builtin_amdgcn_sched_barrier(0);
      }
      #pragma unroll
      for (int tt = 0; tt < 4; ++tt) {
        short8 xf = *reinterpret_cast<const short8*>(&xs[(tt * 16 + l15) * 136 + ks * 32 + grp * 8]);
        #pragma unroll
        for (int dt = 0; dt < 2; ++dt)
          vacc[tt][dt] = __builtin_amdgcn_mfma_f32_16x16x32_bf16(xf, wvc[dt], vacc[tt][dt], 0, 0, 0);
      }
      #pragma unroll
      for (int dt = 0; dt < 2; ++dt) wvc[dt] = wvn[dt];
    }
    #pragma unroll
    for (int k2 = 0; k2 < 2; ++k2)
      #pragma unroll
      for (int dt = 0; dt < 2; ++dt)
        Vp[k2][dt] = pack8f(vacc[2 * k2][dt], vacc[2 * k2 + 1][dt]);
  }

  // ---- prefetch bias-table for mt=0, then barrier (xs reads all done) ----
  const float* tbase = tabf + (((size_t)(wdx * 4 + h)) * 16) * 256;
  float4 tbc[4], tbn[4];
  #pragma unroll
  for (int nt = 0; nt < 4; ++nt)
    tbc[nt] = *reinterpret_cast<const float4*>(tbase + (((size_t)nt) * 64 + lane) * 4);
  __syncthreads();   // B1: ao overlay allowed

  // ---- ones fragment for the denominator MFMA ----
  const short ONEB = (short)0x3F80;    // bf16 1.0
  const short8 ones8 = (short8){ONEB, ONEB, ONEB, ONEB, ONEB, ONEB, ONEB, ONEB};

  // ---- per query-column-tile: S^T, exp2, PV + sum-MFMA -> ao overlay ----
  #pragma unroll
  for (int mt = 0; mt < 4; ++mt) {
    if (mt < 3) {
      #pragma unroll
      for (int nt = 0; nt < 4; ++nt)
        tbn[nt] = *reinterpret_cast<const float4*>(tbase + (((size_t)(mt + 1) * 4 + nt) * 64 + lane) * 4);
      __builtin_amdgcn_sched_barrier(0);
    }
    f32x4 s4[4];
    #pragma unroll
    for (int nt = 0; nt < 4; ++nt)
      s4[nt] = __builtin_amdgcn_mfma_f32_16x16x32_bf16(Kp[nt], Qp[mt], zero4, 0, 0, 0);
    const int m0 = mt * 16 + l15;
    // logits (already *log2e) + bias; no max subtraction (bounded, exp2-safe)
    #pragma unroll
    for (int nt = 0; nt < 4; ++nt) {
      s4[nt][0] = __builtin_amdgcn_exp2f(s4[nt][0] + tbc[nt].x);
      s4[nt][1] = __builtin_amdgcn_exp2f(s4[nt][1] + tbc[nt].y);
      s4[nt][2] = __builtin_amdgcn_exp2f(s4[nt][2] + tbc[nt].z);
      s4[nt][3] = __builtin_amdgcn_exp2f(s4[nt][3] + tbc[nt].w);
    }
    short8 Pp0 = pack8f(s4[0], s4[1]);   // unnormalized P (bf16)
    short8 Pp1 = pack8f(s4[2], s4[3]);
    // denominator: every output row = sum_n P[n][m]; lane-local, no shuffles
    f32x4 sum4 = __builtin_amdgcn_mfma_f32_16x16x32_bf16(ones8, Pp0, zero4, 0, 0, 0);
    sum4 = __builtin_amdgcn_mfma_f32_16x16x32_bf16(ones8, Pp1, sum4, 0, 0, 0);
    #pragma unroll
    for (int dt = 0; dt < 2; ++dt) {
      f32x4 ot = __builtin_amdgcn_mfma_f32_16x16x32_bf16(Vp[0][dt], Pp0, zero4, 0, 0, 0);
      ot = __builtin_amdgcn_mfma_f32_16x16x32_bf16(Vp[1][dt], Pp1, ot, 0, 0, 0);
      float ri = 1.0f / sum4[0];
      *reinterpret_cast<int2*>(&xs[m0 * 136 + h * 32 + dt * 16 + grp * 4]) =
          pack4i(ot[0] * ri, ot[1] * ri, ot[2] * ri, ot[3] * ri);
    }
    #pragma unroll
    for (int nt = 0; nt < 4; ++nt) tbc[nt] = tbn[nt];
  }
  __syncthreads();   // B2: ao complete -> proj reads

  // ---- proj for own 16 token rows; nt-outer loop (pc = one f32x4) ----
  short8 afr[4];
  #pragma unroll
  for (int ks = 0; ks < 4; ++ks)
    afr[ks] = *reinterpret_cast<const short8*>(&xs[(h * 16 + l15) * 136 + ks * 32 + grp * 8]);
  short8 bc[4], bn[4];
  #pragma unroll
  for (int ks = 0; ks < 4; ++ks)
    bc[ks] = *reinterpret_cast<const short8*>(pwsw + (((size_t)0 * 4 + ks) * 64 + lane) * 8);
  #pragma unroll
  for (int nt = 0; nt < 8; ++nt) {
    if (nt < 7) {
      #pragma unroll
      for (int ks = 0; ks < 4; ++ks)
        bn[ks] = *reinterpret_cast<const short8*>(pwsw + (((size_t)(nt + 1) * 4 + ks) * 64 + lane) * 8);
      __builtin_amdgcn_sched_barrier(0);
    }
    float bv = pb[nt * 16 + l15];
    f32x4 pc = (f32x4){bv, bv, bv, bv};
    #pragma unroll
    for (int ks = 0; ks < 4; ++ks)
      pc = __builtin_amdgcn_mfma_f32_16x16x32_bf16(afr[ks], bc[ks], pc, 0, 0, 0);
    #pragma unroll
    for (int r = 0; r < 4; ++r) {
      int m = h * 16 + grp * 4 + r;
      if (m < 49)
        out[xbase + (size_t)m * 128 + nt * 16 + l15] = pc[r];
    }
    #pragma unroll
    for (int ks = 0; ks < 4; ++ks) bc[ks] = bn[ks];
  }
}

// ---------------------------------------------------------------------------
extern "C" void kernel_launch(void* const* d_in, const int* in_sizes, int n_in,
                              void* d_out, int out_size, void* d_ws, size_t ws_size,
                              hipStream_t stream) {
  const float* x    = (const float*)d_in[0];
  const float* mask = (const float*)d_in[1];
  const float* qkvw = (const float*)d_in[2];
  const float* qkvb = (const float*)d_in[3];
  const float* rpb  = (const float*)d_in[4];
  const float* pw   = (const float*)d_in[5];
  const float* pb   = (const float*)d_in[6];
  float* out = (float*)d_out;

  char* ws = (char*)d_ws;
  short* wfsw = (short*)ws;                  // 4*6*4*64*16 B = 98,304 B
  short* pwsw = (short*)(ws + 98304);        // 8*4*64*16 B  = 32,768 B
  float* tabf = (float*)(ws + 131072);       // 256*16*64*16 B = 4,194,304 B

  k_prep <<<264,  256, 0, stream>>>(mask, rpb, qkvw, pw, tabf, wfsw, pwsw);
  k_fused<<<4096, 256, 0, stream>>>(x, qkvb, pb, tabf, wfsw, pwsw, out);
}

// Round 14
// 72.453 us; speedup vs baseline: 1.9714x; 1.0579x over previous
//
#include <hip/hip_runtime.h>
#include <hip/hip_bf16.h>

typedef __attribute__((ext_vector_type(8))) short short8;
typedef __attribute__((ext_vector_type(4))) short short4v;
typedef __attribute__((ext_vector_type(4))) float f32x4;

#define SCALE_QL 0.25504601521753316f   // (1/sqrt(32)) * log2(e)
#define LOG2E    1.4426950408889634f

__device__ __forceinline__ short f2bf(float f) {
  union { float f; unsigned u; } v; v.f = f;
  unsigned r = (v.u + 0x7fffu + ((v.u >> 16) & 1u)) >> 16;
  return (short)r;
}

union S8U { short8 v; __hip_bfloat162 h[4]; int2 d[2]; };
union W4U { int2 d; __hip_bfloat162 h[2]; };

__device__ __forceinline__ short8 pack8i(float4 a, float4 b) {
  S8U r;
  r.h[0] = __float22bfloat162_rn(make_float2(a.x, a.y));
  r.h[1] = __float22bfloat162_rn(make_float2(a.z, a.w));
  r.h[2] = __float22bfloat162_rn(make_float2(b.x, b.y));
  r.h[3] = __float22bfloat162_rn(make_float2(b.z, b.w));
  return r.v;
}

__device__ __forceinline__ short8 pack8f(f32x4 a, f32x4 b) {
  S8U r;
  r.h[0] = __float22bfloat162_rn(make_float2(a[0], a[1]));
  r.h[1] = __float22bfloat162_rn(make_float2(a[2], a[3]));
  r.h[2] = __float22bfloat162_rn(make_float2(b[0], b[1]));
  r.h[3] = __float22bfloat162_rn(make_float2(b[2], b[3]));
  return r.v;
}

__device__ __forceinline__ int2 pack4i(float a, float b, float c, float d) {
  W4U w;
  w.h[0] = __float22bfloat162_rn(make_float2(a, b));
  w.h[1] = __float22bfloat162_rn(make_float2(c, d));
  return w.d;
}

// ---------------------------------------------------------------------------
// k_prep: fragment-major pre-swizzle; bias table pre-multiplied by log2(e).
// ---------------------------------------------------------------------------
__global__ __launch_bounds__(256) void k_prep(
    const float* __restrict__ mask, const float* __restrict__ rpb,
    const float* __restrict__ qkvw, const float* __restrict__ pw,
    float* __restrict__ tabf, short* __restrict__ wfsw, short* __restrict__ pwsw)
{
  const int bid = blockIdx.x, tid = threadIdx.x;
  if (bid < 256) {
    const int wdx = bid >> 2, hh = bid & 3;
    for (int i = 0; i < 4; ++i) {
      int e = tid + i * 256;                 // [mt][nt][lane]
      int mt = e >> 8, nt = (e >> 6) & 3, ln = e & 63;
      int l = ln & 15, g = ln >> 4;
      int m = mt * 16 + l, n0 = nt * 16 + g * 4;
      float vv[4];
      #pragma unroll
      for (int j = 0; j < 4; ++j) {
        int n = n0 + j;
        float val;
        if (n >= 49)      val = -1e30f;
        else if (m >= 49) val = 0.0f;
        else {
          int mi = (m * 37) >> 8, mj = m - mi * 7;
          int ni = (n * 37) >> 8, nj = n - ni * 7;
          int ridx = (mi - ni + 6) * 13 + (mj - nj + 6);
          val = mask[(size_t)wdx * 2401 + m * 49 + n] + rpb[ridx * 4 + hh];
        }
        vv[j] = val * LOG2E;
      }
      float4* dst = reinterpret_cast<float4*>(&tabf[((size_t)bid * 1024 + e) * 4]);
      *dst = make_float4(vv[0], vv[1], vv[2], vv[3]);
    }
  } else {
    int e0 = (bid - 256) * 256 + tid;
    for (int i = 0; i < 4; ++i) {
      int e = e0 + i * 2048;
      const float* src;
      short* dst;
      if (e < 6144) {
        int hh = e / 1536, rem = e - hh * 1536;
        int slot = rem >> 8, ks = (rem >> 6) & 3, ln = rem & 63;
        int l = ln & 15, g = ln >> 4;
        int r = (slot >> 1) * 128 + hh * 32 + (slot & 1) * 16 + l;
        int c = ks * 32 + g * 8;
        src = &qkvw[(size_t)r * 128 + c];
        dst = wfsw + (size_t)e * 8;
      } else {
        int p = e - 6144;
        int nt = p >> 8, ks = (p >> 6) & 3, ln = p & 63;
        int l = ln & 15, g = ln >> 4;
        int r = nt * 16 + l, c = ks * 32 + g * 8;
        src = &pw[(size_t)r * 128 + c];
        dst = pwsw + (size_t)p * 8;
      }
      float4 a = *reinterpret_cast<const float4*>(src);
      float4 b = *reinterpret_cast<const float4*>(src + 4);
      *reinterpret_cast<short8*>(dst) = pack8i(a, b);
    }
  }
}

// ---------------------------------------------------------------------------
// k_fused: round-13 structure (1 window/block, 4 waves, shuffle-free softmax)
// NEW: all load pipelines preload-2-upfront / reload-after-use (2x issue
// distance, same register count); proj B-frags + pb hoisted before barrier
// B2 (latency overlaps barrier wait); raw v_rcp for the softmax denominator.
// ---------------------------------------------------------------------------
__global__ __launch_bounds__(256, 3) void k_fused(
    const float* __restrict__ x, const float* __restrict__ qkvb,
    const float* __restrict__ pb, const float* __restrict__ tabf,
    const short* __restrict__ wfsw, const short* __restrict__ pwsw,
    float* __restrict__ out)
{
  __shared__ short xs[64 * 136];       // x bf16 [64][136]; later ao overlay
  const int tid = threadIdx.x;
  const int lane = tid & 63;
  const int h = tid >> 6;
  const int l15 = lane & 15, grp = lane >> 4;
  // XCD-affinity swizzle: bijective on [0,4096); wdx mod 8 == blockIdx mod 8
  const int bswz = blockIdx.x;
  const int gwin = ((bswz >> 6) << 6) + (bswz & 7) + ((bswz >> 3) & 7) * 8;
  const int wdx = gwin & 63;
  const size_t xbase = (size_t)gwin * 49 * 128;
  const short* wfh = wfsw + (size_t)h * 6 * 4 * 64 * 8;
  const f32x4 zero4 = (f32x4){0, 0, 0, 0};

  // ---- stage x (fp32 -> bf16 via cvt_pk, coalesced) + zero pad rows ----
  #pragma unroll
  for (int i = 0; i < 7; ++i) {
    int idx = tid + i * 256;
    if (idx < 1568) {
      int r = idx >> 5, c4 = idx & 31;
      float4 v = *reinterpret_cast<const float4*>(&x[xbase + (size_t)r * 128 + c4 * 4]);
      *reinterpret_cast<int2*>(&xs[r * 136 + c4 * 4]) = pack4i(v.x, v.y, v.z, v.w);
    }
  }
  #pragma unroll
  for (int i = 0; i < 4; ++i) {
    int idx = tid + i * 256;
    if (idx < 960) {
      int r = 49 + (idx >> 6), c = idx & 63;
      *reinterpret_cast<int*>(&xs[r * 136 + c * 2]) = 0;
    }
  }
  __syncthreads();

  // ---- QK gemm (swapped), depth-2 wf pipeline ----
  f32x4 qk[4][4];
  #pragma unroll
  for (int nt = 0; nt < 4; ++nt) {
    int base = (nt < 2 ? 0 : 128) + h * 32 + (nt & 1) * 16 + grp * 4;
    float4 b4 = *reinterpret_cast<const float4*>(&qkvb[base]);
    #pragma unroll
    for (int tt = 0; tt < 4; ++tt) qk[tt][nt] = (f32x4){b4.x, b4.y, b4.z, b4.w};
  }
  {
    short8 wf2[2][4];
    #pragma unroll
    for (int p = 0; p < 2; ++p)
      #pragma unroll
      for (int nt = 0; nt < 4; ++nt)
        wf2[p][nt] = *reinterpret_cast<const short8*>(wfh + (((size_t)nt * 4 + p) * 64 + lane) * 8);
    __builtin_amdgcn_sched_barrier(0);
    #pragma unroll
    for (int ks = 0; ks < 4; ++ks) {
      const int b = ks & 1;
      #pragma unroll
      for (int tt = 0; tt < 4; ++tt) {
        short8 xf = *reinterpret_cast<const short8*>(&xs[(tt * 16 + l15) * 136 + ks * 32 + grp * 8]);
        #pragma unroll
        for (int nt = 0; nt < 4; ++nt)
          qk[tt][nt] = __builtin_amdgcn_mfma_f32_16x16x32_bf16(wf2[b][nt], xf, qk[tt][nt], 0, 0, 0);
      }
      if (ks < 2) {
        #pragma unroll
        for (int nt = 0; nt < 4; ++nt)
          wf2[b][nt] = *reinterpret_cast<const short8*>(wfh + (((size_t)nt * 4 + ks + 2) * 64 + lane) * 8);
        __builtin_amdgcn_sched_barrier(0);
      }
    }
  }
  short8 Qp[4], Kp[4];
  #pragma unroll
  for (int tt = 0; tt < 4; ++tt) {
    Qp[tt] = pack8f(qk[tt][0] * SCALE_QL, qk[tt][1] * SCALE_QL);  // log2e folded
    Kp[tt] = pack8f(qk[tt][2], qk[tt][3]);
  }

  // ---- V gemm (normal orientation), depth-2 wv pipeline ----
  short8 Vp[2][2];
  {
    f32x4 vacc[4][2];
    #pragma unroll
    for (int dt = 0; dt < 2; ++dt) {
      float bv = qkvb[256 + h * 32 + dt * 16 + l15];
      #pragma unroll
      for (int tt = 0; tt < 4; ++tt) vacc[tt][dt] = (f32x4){bv, bv, bv, bv};
    }
    short8 wv2[2][2];
    #pragma unroll
    for (int p = 0; p < 2; ++p)
      #pragma unroll
      for (int dt = 0; dt < 2; ++dt)
        wv2[p][dt] = *reinterpret_cast<const short8*>(wfh + ((((size_t)4 + dt) * 4 + p) * 64 + lane) * 8);
    __builtin_amdgcn_sched_barrier(0);
    #pragma unroll
    for (int ks = 0; ks < 4; ++ks) {
      const int b = ks & 1;
      #pragma unroll
      for (int tt = 0; tt < 4; ++tt) {
        short8 xf = *reinterpret_cast<const short8*>(&xs[(tt * 16 + l15) * 136 + ks * 32 + grp * 8]);
        #pragma unroll
        for (int dt = 0; dt < 2; ++dt)
          vacc[tt][dt] = __builtin_amdgcn_mfma_f32_16x16x32_bf16(xf, wv2[b][dt], vacc[tt][dt], 0, 0, 0);
      }
      if (ks < 2) {
        #pragma unroll
        for (int dt = 0; dt < 2; ++dt)
          wv2[b][dt] = *reinterpret_cast<const short8*>(wfh + ((((size_t)4 + dt) * 4 + ks + 2) * 64 + lane) * 8);
        __builtin_amdgcn_sched_barrier(0);
      }
    }
    #pragma unroll
    for (int k2 = 0; k2 < 2; ++k2)
      #pragma unroll
      for (int dt = 0; dt < 2; ++dt)
        Vp[k2][dt] = pack8f(vacc[2 * k2][dt], vacc[2 * k2 + 1][dt]);
  }

  // ---- prefetch bias-table for mt=0, then barrier (xs reads all done) ----
  const float* tbase = tabf + (((size_t)(wdx * 4 + h)) * 16) * 256;
  float4 tbc[4], tbn[4];
  #pragma unroll
  for (int nt = 0; nt < 4; ++nt)
    tbc[nt] = *reinterpret_cast<const float4*>(tbase + (((size_t)nt) * 64 + lane) * 4);
  __syncthreads();   // B1: ao overlay allowed

  // ---- ones fragment for the denominator MFMA ----
  const short ONEB = (short)0x3F80;    // bf16 1.0
  const short8 ones8 = (short8){ONEB, ONEB, ONEB, ONEB, ONEB, ONEB, ONEB, ONEB};

  // ---- per query-column-tile: S^T, exp2, PV + sum-MFMA -> ao overlay ----
  #pragma unroll
  for (int mt = 0; mt < 4; ++mt) {
    if (mt < 3) {
      #pragma unroll
      for (int nt = 0; nt < 4; ++nt)
        tbn[nt] = *reinterpret_cast<const float4*>(tbase + (((size_t)(mt + 1) * 4 + nt) * 64 + lane) * 4);
      __builtin_amdgcn_sched_barrier(0);
    }
    f32x4 s4[4];
    #pragma unroll
    for (int nt = 0; nt < 4; ++nt)
      s4[nt] = __builtin_amdgcn_mfma_f32_16x16x32_bf16(Kp[nt], Qp[mt], zero4, 0, 0, 0);
    const int m0 = mt * 16 + l15;
    // logits (already *log2e) + bias; no max subtraction (bounded, exp2-safe)
    #pragma unroll
    for (int nt = 0; nt < 4; ++nt) {
      s4[nt][0] = __builtin_amdgcn_exp2f(s4[nt][0] + tbc[nt].x);
      s4[nt][1] = __builtin_amdgcn_exp2f(s4[nt][1] + tbc[nt].y);
      s4[nt][2] = __builtin_amdgcn_exp2f(s4[nt][2] + tbc[nt].z);
      s4[nt][3] = __builtin_amdgcn_exp2f(s4[nt][3] + tbc[nt].w);
    }
    short8 Pp0 = pack8f(s4[0], s4[1]);   // unnormalized P (bf16)
    short8 Pp1 = pack8f(s4[2], s4[3]);
    // denominator: every output row = sum_n P[n][m]; lane-local, no shuffles
    f32x4 sum4 = __builtin_amdgcn_mfma_f32_16x16x32_bf16(ones8, Pp0, zero4, 0, 0, 0);
    sum4 = __builtin_amdgcn_mfma_f32_16x16x32_bf16(ones8, Pp1, sum4, 0, 0, 0);
    float ri = __builtin_amdgcn_rcpf(sum4[0]);
    #pragma unroll
    for (int dt = 0; dt < 2; ++dt) {
      f32x4 ot = __builtin_amdgcn_mfma_f32_16x16x32_bf16(Vp[0][dt], Pp0, zero4, 0, 0, 0);
      ot = __builtin_amdgcn_mfma_f32_16x16x32_bf16(Vp[1][dt], Pp1, ot, 0, 0, 0);
      *reinterpret_cast<int2*>(&xs[m0 * 136 + h * 32 + dt * 16 + grp * 4]) =
          pack4i(ot[0] * ri, ot[1] * ri, ot[2] * ri, ot[3] * ri);
    }
    #pragma unroll
    for (int nt = 0; nt < 4; ++nt) tbc[nt] = tbn[nt];
  }

  // ---- hoist proj B-frags (nt=0,1) and pb before B2: latency under barrier --
  short8 pw2[2][4];
  #pragma unroll
  for (int p = 0; p < 2; ++p)
    #pragma unroll
    for (int ks = 0; ks < 4; ++ks)
      pw2[p][ks] = *reinterpret_cast<const short8*>(pwsw + (((size_t)p * 4 + ks) * 64 + lane) * 8);
  float pbv[2];
  pbv[0] = pb[l15];
  pbv[1] = pb[16 + l15];
  __syncthreads();   // B2: ao complete -> proj reads

  // ---- proj for own 16 token rows; depth-2 B pipeline ----
  short8 afr[4];
  #pragma unroll
  for (int ks = 0; ks < 4; ++ks)
    afr[ks] = *reinterpret_cast<const short8*>(&xs[(h * 16 + l15) * 136 + ks * 32 + grp * 8]);
  #pragma unroll
  for (int nt = 0; nt < 8; ++nt) {
    const int b = nt & 1;
    float bv = (nt < 2) ? pbv[nt] : pb[nt * 16 + l15];
    f32x4 pc = (f32x4){bv, bv, bv, bv};
    #pragma unroll
    for (int ks = 0; ks < 4; ++ks)
      pc = __builtin_amdgcn_mfma_f32_16x16x32_bf16(afr[ks], pw2[b][ks], pc, 0, 0, 0);
    if (nt < 6) {
      #pragma unroll
      for (int ks = 0; ks < 4; ++ks)
        pw2[b][ks] = *reinterpret_cast<const short8*>(pwsw + (((size_t)(nt + 2) * 4 + ks) * 64 + lane) * 8);
      __builtin_amdgcn_sched_barrier(0);
    }
    #pragma unroll
    for (int r = 0; r < 4; ++r) {
      int m = h * 16 + grp * 4 + r;
      if (m < 49)
        out[xbase + (size_t)m * 128 + nt * 16 + l15] = pc[r];
    }
  }
}

// ---------------------------------------------------------------------------
extern "C" void kernel_launch(void* const* d_in, const int* in_sizes, int n_in,
                              void* d_out, int out_size, void* d_ws, size_t ws_size,
                              hipStream_t stream) {
  const float* x    = (const float*)d_in[0];
  const float* mask = (const float*)d_in[1];
  const float* qkvw = (const float*)d_in[2];
  const float* qkvb = (const float*)d_in[3];
  const float* rpb  = (const float*)d_in[4];
  const float* pw   = (const float*)d_in[5];
  const float* pb   = (const float*)d_in[6];
  float* out = (float*)d_out;

  char* ws = (char*)d_ws;
  short* wfsw = (short*)ws;                  // 4*6*4*64*16 B = 98,304 B
  short* pwsw = (short*)(ws + 98304);        // 8*4*64*16 B  = 32,768 B
  float* tabf = (float*)(ws + 131072);       // 256*16*64*16 B = 4,194,304 B

  k_prep <<<264,  256, 0, stream>>>(mask, rpb, qkvw, pw, tabf, wfsw, pwsw);
  k_fused<<<4096, 256, 0, stream>>>(x, qkvb, pb, tabf, wfsw, pwsw, out);
}